// Round 9
// baseline (582.028 us; speedup 1.0000x reference)
//
#include <hip/hip_runtime.h>

#define TOK 4096
#define NE 16
#define HD 2048
#define ID 1024
#define QGROUP 16
#define CAP 4096

typedef _Float16 half4v __attribute__((ext_vector_type(4)));
typedef _Float16 half8v __attribute__((ext_vector_type(8)));
typedef float float4v __attribute__((ext_vector_type(4)));

__device__ __forceinline__ void g2l16(const void* g, void* l) {
    __builtin_amdgcn_global_load_lds(
        (const __attribute__((address_space(1))) unsigned int*)g,
        (__attribute__((address_space(3))) unsigned int*)l, 16, 0, 0);
}

// ---------------- prep: x fp32 -> f16 ----------------
__global__ __launch_bounds__(256) void prep_kernel(
    const float* __restrict__ x, _Float16* __restrict__ xh)
{
    int i8 = (blockIdx.x * 256 + threadIdx.x) * 8;
    float4 f0 = *(const float4*)&x[i8];
    float4 f1 = *(const float4*)&x[i8 + 4];
    half8v h;
    h[0] = (_Float16)f0.x; h[1] = (_Float16)f0.y; h[2] = (_Float16)f0.z; h[3] = (_Float16)f0.w;
    h[4] = (_Float16)f1.x; h[5] = (_Float16)f1.y; h[6] = (_Float16)f1.z; h[7] = (_Float16)f1.w;
    *(half8v*)&xh[i8] = h;
}

// ---------------- router: per-token top2, NO atomics ----------------
__global__ __launch_bounds__(256) void router_kernel(
    const float* __restrict__ x, const float* __restrict__ gw,
    int* __restrict__ topi, float* __restrict__ topw)
{
    int t = blockIdx.x;
    int tid = threadIdx.x;
    float p[NE];
#pragma unroll
    for (int e = 0; e < NE; e++) p[e] = 0.f;
    const float* xr = x + (size_t)t * HD;
    for (int h = tid; h < HD; h += 256) {
        float xv = xr[h];
#pragma unroll
        for (int e = 0; e < NE; e++) p[e] = fmaf(xv, gw[e * HD + h], p[e]);
    }
#pragma unroll
    for (int off = 32; off > 0; off >>= 1) {
#pragma unroll
        for (int e = 0; e < NE; e++) p[e] += __shfl_down(p[e], off, 64);
    }
    __shared__ float part[4][NE];
    int wave = tid >> 6, lane = tid & 63;
    if (lane == 0) {
#pragma unroll
        for (int e = 0; e < NE; e++) part[wave][e] = p[e];
    }
    __syncthreads();
    if (tid == 0) {
        float s[NE]; float sum = 0.f;
#pragma unroll
        for (int e = 0; e < NE; e++) {
            float l = part[0][e] + part[1][e] + part[2][e] + part[3][e];
            float sg = 1.f / (1.f + expf(-l));
            s[e] = sg; sum += sg;
        }
        int i1 = 0;
#pragma unroll
        for (int e = 1; e < NE; e++) if (s[e] > s[i1]) i1 = e;
        int i2 = (i1 == 0) ? 1 : 0;
#pragma unroll
        for (int e = 0; e < NE; e++) if (e != i1 && s[e] > s[i2]) i2 = e;
        float p1 = s[i1] / sum, p2 = s[i2] / sum;
        float inv = 1.f / (p1 + p2 + 1e-20f);
        topi[t * 2 + 0] = i1; topw[t * 2 + 0] = p1 * inv;
        topi[t * 2 + 1] = i2; topw[t * 2 + 1] = p2 * inv;
    }
}

// ---------------- compaction: one block per expert, deterministic ordered scan ----------------
__global__ __launch_bounds__(256) void compact_kernel(
    const int* __restrict__ topi, const float* __restrict__ topw,
    int* __restrict__ counts, int* __restrict__ pair_row, float* __restrict__ pair_w)
{
    const int e = blockIdx.x;
    const int tid = threadIdx.x;
    const int lane = tid & 63, wv = tid >> 6;
    __shared__ int wsum[4];
    int running = 0;
    for (int base = 0; base < 2 * TOK; base += 256) {
        const int idx = base + tid;
        const bool f = (topi[idx] == e);
        unsigned long long b = __ballot(f);
        int pre = __popcll(b & ((1ull << lane) - 1ull));
        if (lane == 0) wsum[wv] = __popcll(b);
        __syncthreads();
        int woff = 0;
#pragma unroll
        for (int w = 0; w < 4; w++) if (w < wv) woff += wsum[w];
        const int tot = wsum[0] + wsum[1] + wsum[2] + wsum[3];
        if (f) {
            const int pos = running + woff + pre;
            pair_row[e * CAP + pos] = idx;          // pair id = t*2+slot
            pair_w[e * CAP + pos] = topw[idx];
        }
        running += tot;
        __syncthreads();
    }
    if (tid == 0) counts[e] = running;
}

// ---------------- dequant + transpose: codes [E][K][N] int32 -> f16 [E][N][K] ----------------
template<int K, int N>
__global__ __launch_bounds__(256) void dequantT_kernel(
    const int* __restrict__ qw, const float* __restrict__ bsc, _Float16* __restrict__ wq)
{
    const int e = blockIdx.z, kt = blockIdx.y, nt = blockIdx.x;
    const int tid = threadIdx.x;
    __shared__ _Float16 T[64][68];   // [k][n]

    const int c4 = (tid & 15) * 4;
    const int r0 = tid >> 4;         // 0..15
#pragma unroll
    for (int p = 0; p < 4; p++) {
        const int r = p * 16 + r0;
        const int kabs = kt * 64 + r;
        const int4 c = *(const int4*)&qw[((size_t)e * K + kabs) * N + nt * 64 + c4];
        const float4 sc = *(const float4*)&bsc[((size_t)e * (K / QGROUP) + (kabs >> 4)) * N + nt * 64 + c4];
        half4v h;
        h[0] = (_Float16)((float)(c.x - 8) * sc.x);
        h[1] = (_Float16)((float)(c.y - 8) * sc.y);
        h[2] = (_Float16)((float)(c.z - 8) * sc.z);
        h[3] = (_Float16)((float)(c.w - 8) * sc.w);
        *(half4v*)&T[r][c4] = h;
    }
    __syncthreads();
    const int nrow = tid >> 2;
    const int kseg = (tid & 3) * 16;
    half8v o0, o1;
#pragma unroll
    for (int i = 0; i < 8; i++) o0[i] = T[kseg + i][nrow];
#pragma unroll
    for (int i = 0; i < 8; i++) o1[i] = T[kseg + 8 + i][nrow];
    _Float16* dst = wq + ((size_t)e * N + nt * 64 + nrow) * K + kt * 64 + kseg;
    *(half8v*)dst = o0;
    *(half8v*)(dst + 8) = o1;
}

// ---------------- high-occupancy m97-style grouped GEMM ----------------
// Tile 64M x 128N x BK=32, 256 threads (4 waves as 2x2: each 32Mx64N, 2x4 frags).
// 1-D grid XCD-swizzled so M-siblings (same B tile) share an XCD's L2.
template<int N, int K, bool UP>
__global__ __launch_bounds__(256, 4) void gemm4_kernel(
    const _Float16* __restrict__ A, const _Float16* __restrict__ BT,
    const float* __restrict__ gsc,
    const int* __restrict__ counts, const int* __restrict__ pair_row,
    const float* __restrict__ pair_w,
    _Float16* __restrict__ store16, float* __restrict__ store32)
{
    constexpr int NT = N / 128;
    constexpr int MT = CAP / 64;              // 64
    const int bx = blockIdx.x;
    const int g8 = bx & 7;                    // XCD hint
    const int rest = bx >> 3;
    const int m = rest % MT;
    const int g = (rest / MT) * 8 + g8;       // g in [0, NT*NE), multiple of 8 guaranteed
    const int e = g / NT, nt = g % NT;
    const int cnt = counts[e];
    const int mbase = m * 64;
    if (mbase >= cnt) return;
    const int nbase = nt * 128;
    const int tid = threadIdx.x;

    __shared__ _Float16 As[64 * 32];          // [m][k], 64-B rows (g2l16, no padding)
    __shared__ _Float16 Bs[128 * 32];         // [n][k]
    __shared__ int rows_s[64];
    __shared__ float pw_s[64];

    if (tid < 64) {
        int idx = mbase + tid; if (idx >= cnt) idx = cnt - 1;
        rows_s[tid] = pair_row[e * CAP + idx];
        pw_s[tid] = UP ? pair_w[e * CAP + idx] : 0.f;
    }
    __syncthreads();

    // staging: thread -> 16-B slot; A: 256 slots (1/thread), B: 512 slots (2/thread)
    const int arow = tid >> 2, akc = tid & 3;
    const int pra = rows_s[arow];
    const _Float16* asrc  = A + (size_t)(UP ? (pra >> 1) : pra) * K + akc * 8;
    const _Float16* bsrc0 = BT + ((size_t)e * N + nbase + arow) * K + akc * 8;
    const _Float16* bsrc1 = bsrc0 + (size_t)64 * K;
    _Float16* adst  = &As[tid * 8];
    _Float16* bdst0 = &Bs[tid * 8];
    _Float16* bdst1 = &Bs[2048 + tid * 8];

    const int lane = tid & 63, wv = tid >> 6;
    const int quad = lane >> 4, lm = lane & 15;
    const int wm = (wv & 1) * 32, wn = (wv >> 1) * 64;

    float4v acc[2][4];
#pragma unroll
    for (int mi = 0; mi < 2; mi++)
#pragma unroll
        for (int ni = 0; ni < 4; ni++) acc[mi][ni] = (float4v){0.f, 0.f, 0.f, 0.f};

    for (int k0 = 0; k0 < K; k0 += 32) {
        g2l16(asrc + k0, adst);
        g2l16(bsrc0 + k0, bdst0);
        g2l16(bsrc1 + k0, bdst1);
        __syncthreads();
        half8v af[2], bf[4];
#pragma unroll
        for (int mi = 0; mi < 2; mi++)
            af[mi] = *(const half8v*)&As[(wm + mi * 16 + lm) * 32 + quad * 8];
#pragma unroll
        for (int ni = 0; ni < 4; ni++)
            bf[ni] = *(const half8v*)&Bs[(wn + ni * 16 + lm) * 32 + quad * 8];
#pragma unroll
        for (int mi = 0; mi < 2; mi++)
#pragma unroll
            for (int ni = 0; ni < 4; ni++)
                acc[mi][ni] = __builtin_amdgcn_mfma_f32_16x16x32_f16(af[mi], bf[ni], acc[mi][ni], 0, 0, 0);
        __syncthreads();
    }

    const float gs = gsc[0];
#pragma unroll
    for (int mi = 0; mi < 2; mi++) {
#pragma unroll
        for (int r = 0; r < 4; r++) {
            const int rl = wm + mi * 16 + quad * 4 + r;
            if (mbase + rl < cnt) {
                const int pr = rows_s[rl];
#pragma unroll
                for (int ni = 0; ni < 4; ni++) {
                    const int col = nbase + wn + ni * 16 + lm;
                    float v = acc[mi][ni][r] * gs;
                    if (UP) {
                        v = fmaxf(v, 0.f);
                        v = v * v * pw_s[rl];
                        store16[(size_t)pr * N + col] = (_Float16)v;
                    } else {
                        atomicAdd(&store32[(size_t)(pr >> 1) * N + col], v);
                    }
                }
            }
        }
    }
}

// ---------------- fallback fused-dequant GEMM (round-4 structure) ----------------
template<int N, int K, bool UP>
__global__ __launch_bounds__(256) void gemm_fused_kernel(
    const _Float16* __restrict__ A, const int* __restrict__ qw,
    const float* __restrict__ bsc, const float* __restrict__ gsc,
    const int* __restrict__ counts, const int* __restrict__ pair_row,
    const float* __restrict__ pair_w,
    _Float16* __restrict__ store16, float* __restrict__ store32)
{
    constexpr int NT = N / 128;
    const int e = blockIdx.y;
    const int cnt = counts[e];
    const int mt = blockIdx.x / NT, nt = blockIdx.x % NT;
    const int mbase = mt * 128;
    if (mbase >= cnt) return;
    const int nbase = nt * 128;
    const int tid = threadIdx.x;

    __shared__ _Float16 As[128][40];
    __shared__ _Float16 Bs[128][40];
    __shared__ int rows_s[128];
    __shared__ float pw_s[128];

    if (tid < 128) {
        int idx = mbase + tid; if (idx >= cnt) idx = cnt - 1;
        rows_s[tid] = pair_row[e * CAP + idx];
        pw_s[tid] = UP ? pair_w[e * CAP + idx] : 0.f;
    }

    const int lane = tid & 63, wv = tid >> 6;
    const int quad = lane >> 4, lm = lane & 15;
    const int wr = (wv >> 1) * 64, wc = (wv & 1) * 64;

    float4v acc[4][4];
#pragma unroll
    for (int mi = 0; mi < 4; mi++)
#pragma unroll
        for (int ni = 0; ni < 4; ni++) acc[mi][ni] = (float4v){0.f, 0.f, 0.f, 0.f};

    const int am = tid & 127, akk = (tid >> 7) * 16;
    const int bn4 = (tid & 31) * 4, bkb = (tid >> 5) * 4;

    for (int k0 = 0; k0 < K; k0 += 32) {
        __syncthreads();
        {
            int pr = rows_s[am];
            const _Float16* src = A + (size_t)(UP ? (pr >> 1) : pr) * K + k0 + akk;
            *(uint4*)&As[am][akk] = *(const uint4*)src;
            *(uint4*)&As[am][akk + 8] = *(const uint4*)(src + 8);
        }
        {
            const int kabs = k0 + bkb;
            const float4 sc = *(const float4*)&bsc[((size_t)e * (K / QGROUP) + (kabs >> 4)) * N + nbase + bn4];
            const int4 c0 = *(const int4*)&qw[((size_t)e * K + kabs + 0) * N + nbase + bn4];
            const int4 c1 = *(const int4*)&qw[((size_t)e * K + kabs + 1) * N + nbase + bn4];
            const int4 c2 = *(const int4*)&qw[((size_t)e * K + kabs + 2) * N + nbase + bn4];
            const int4 c3 = *(const int4*)&qw[((size_t)e * K + kabs + 3) * N + nbase + bn4];
            half4v q;
            q[0] = (_Float16)((c0.x - 8) * sc.x); q[1] = (_Float16)((c1.x - 8) * sc.x);
            q[2] = (_Float16)((c2.x - 8) * sc.x); q[3] = (_Float16)((c3.x - 8) * sc.x);
            *(half4v*)&Bs[bn4 + 0][bkb] = q;
            q[0] = (_Float16)((c0.y - 8) * sc.y); q[1] = (_Float16)((c1.y - 8) * sc.y);
            q[2] = (_Float16)((c2.y - 8) * sc.y); q[3] = (_Float16)((c3.y - 8) * sc.y);
            *(half4v*)&Bs[bn4 + 1][bkb] = q;
            q[0] = (_Float16)((c0.z - 8) * sc.z); q[1] = (_Float16)((c1.z - 8) * sc.z);
            q[2] = (_Float16)((c2.z - 8) * sc.z); q[3] = (_Float16)((c3.z - 8) * sc.z);
            *(half4v*)&Bs[bn4 + 2][bkb] = q;
            q[0] = (_Float16)((c0.w - 8) * sc.w); q[1] = (_Float16)((c1.w - 8) * sc.w);
            q[2] = (_Float16)((c2.w - 8) * sc.w); q[3] = (_Float16)((c3.w - 8) * sc.w);
            *(half4v*)&Bs[bn4 + 3][bkb] = q;
        }
        __syncthreads();
        half8v af[4], bf[4];
#pragma unroll
        for (int mi = 0; mi < 4; mi++)
            af[mi] = *(const half8v*)&As[wr + mi * 16 + lm][quad * 8];
#pragma unroll
        for (int ni = 0; ni < 4; ni++)
            bf[ni] = *(const half8v*)&Bs[wc + ni * 16 + lm][quad * 8];
#pragma unroll
        for (int mi = 0; mi < 4; mi++)
#pragma unroll
            for (int ni = 0; ni < 4; ni++)
                acc[mi][ni] = __builtin_amdgcn_mfma_f32_16x16x32_f16(af[mi], bf[ni], acc[mi][ni], 0, 0, 0);
    }

    const float gs = gsc[0];
#pragma unroll
    for (int mi = 0; mi < 4; mi++) {
#pragma unroll
        for (int r = 0; r < 4; r++) {
            const int rl = wr + mi * 16 + quad * 4 + r;
            if (mbase + rl < cnt) {
                const int pr = rows_s[rl];
#pragma unroll
                for (int ni = 0; ni < 4; ni++) {
                    const int col = nbase + wc + ni * 16 + lm;
                    float v = acc[mi][ni][r] * gs;
                    if (UP) {
                        v = fmaxf(v, 0.f);
                        v = v * v * pw_s[rl];
                        store16[(size_t)pr * N + col] = (_Float16)v;
                    } else {
                        atomicAdd(&store32[(size_t)(pr >> 1) * N + col], v);
                    }
                }
            }
        }
    }
}

extern "C" void kernel_launch(void* const* d_in, const int* in_sizes, int n_in,
                              void* d_out, int out_size, void* d_ws, size_t ws_size,
                              hipStream_t stream) {
    const float* x   = (const float*)d_in[0];
    const float* gw  = (const float*)d_in[1];
    const float* usc = (const float*)d_in[2];
    const float* ugs = (const float*)d_in[3];
    const float* dsc = (const float*)d_in[4];
    const float* dgs = (const float*)d_in[5];
    const int*   uq  = (const int*)d_in[6];
    const int*   dq  = (const int*)d_in[7];
    float* out = (float*)d_out;

    char* ws = (char*)d_ws;
    int*   counts   = (int*)(ws + 0);
    int*   pair_row = (int*)(ws + 4096);
    float* pair_w   = (float*)(ws + 4096 + (size_t)NE * CAP * 4);        // @266240
    _Float16* xh    = (_Float16*)(ws + 528384);                          // TOK*HD f16 (16.78 MB)
    _Float16* act   = (_Float16*)(ws + 528384 + (size_t)TOK * HD * 2);   // 2*TOK*ID f16 @17.3 MB
    _Float16* wq    = (_Float16*)(ws + 528384 + (size_t)TOK * HD * 2
                                  + (size_t)2 * TOK * ID * 2);           // @34.1 MB, 67.1 MB (reused)
    // topi/topw alias the wq region (lifetime: router -> compact, before dequant writes wq)
    int*   topi = (int*)wq;
    float* topw = (float*)((char*)wq + (size_t)2 * TOK * 4);
    const size_t need_deq = 34082816ull + (size_t)NE * HD * ID * 2;      // ~101.2 MB (confirmed fits)
    const bool use_deq = ws_size >= need_deq;

    hipMemsetAsync(out, 0, (size_t)TOK * HD * 4, stream);   // down-proj accumulates atomically

    prep_kernel<<<(TOK * HD) / (256 * 8), 256, 0, stream>>>(x, xh);
    router_kernel<<<TOK, 256, 0, stream>>>(x, gw, topi, topw);
    compact_kernel<<<NE, 256, 0, stream>>>(topi, topw, counts, pair_row, pair_w);

    if (use_deq) {
        // up: K=HD=2048, N=ID=1024
        dequantT_kernel<HD, ID><<<dim3(ID / 64, HD / 64, NE), 256, 0, stream>>>(uq, usc, wq);
        gemm4_kernel<ID, HD, true><<<(CAP / 64) * (ID / 128) * NE, 256, 0, stream>>>(
            xh, wq, ugs, counts, pair_row, pair_w, act, nullptr);
        // down: K=ID=1024, N=HD=2048 (reuse wq)
        dequantT_kernel<ID, HD><<<dim3(HD / 64, ID / 64, NE), 256, 0, stream>>>(dq, dsc, wq);
        gemm4_kernel<HD, ID, false><<<(CAP / 64) * (HD / 128) * NE, 256, 0, stream>>>(
            act, wq, dgs, counts, pair_row, pair_w, nullptr, out);
    } else {
        gemm_fused_kernel<ID, HD, true><<<dim3((CAP / 128) * (ID / 128), NE), 256, 0, stream>>>(
            xh, uq, usc, ugs, counts, pair_row, pair_w, act, nullptr);
        gemm_fused_kernel<HD, ID, false><<<dim3((CAP / 128) * (HD / 128), NE), 256, 0, stream>>>(
            act, dq, dsc, dgs, counts, pair_row, pair_w, nullptr, out);
    }
}

// Round 10
// 532.240 us; speedup vs baseline: 1.0935x; 1.0935x over previous
//
#include <hip/hip_runtime.h>

#define TOK 4096
#define NE 16
#define HD 2048
#define ID 1024
#define QGROUP 16
#define CAP 4096

typedef _Float16 half4v __attribute__((ext_vector_type(4)));
typedef _Float16 half8v __attribute__((ext_vector_type(8)));
typedef float float4v __attribute__((ext_vector_type(4)));

__device__ __forceinline__ void g2l16(const void* g, void* l) {
    __builtin_amdgcn_global_load_lds(
        (const __attribute__((address_space(1))) unsigned int*)g,
        (__attribute__((address_space(3))) unsigned int*)l, 16, 0, 0);
}

// ---------------- prep: x fp32 -> f16 ----------------
__global__ __launch_bounds__(256) void prep_kernel(
    const float* __restrict__ x, _Float16* __restrict__ xh)
{
    int i8 = (blockIdx.x * 256 + threadIdx.x) * 8;
    float4 f0 = *(const float4*)&x[i8];
    float4 f1 = *(const float4*)&x[i8 + 4];
    half8v h;
    h[0] = (_Float16)f0.x; h[1] = (_Float16)f0.y; h[2] = (_Float16)f0.z; h[3] = (_Float16)f0.w;
    h[4] = (_Float16)f1.x; h[5] = (_Float16)f1.y; h[6] = (_Float16)f1.z; h[7] = (_Float16)f1.w;
    *(half8v*)&xh[i8] = h;
}

// ---------------- router: per-token top2, NO atomics ----------------
__global__ __launch_bounds__(256) void router_kernel(
    const float* __restrict__ x, const float* __restrict__ gw,
    int* __restrict__ topi, float* __restrict__ topw)
{
    int t = blockIdx.x;
    int tid = threadIdx.x;
    float p[NE];
#pragma unroll
    for (int e = 0; e < NE; e++) p[e] = 0.f;
    const float* xr = x + (size_t)t * HD;
    for (int h = tid; h < HD; h += 256) {
        float xv = xr[h];
#pragma unroll
        for (int e = 0; e < NE; e++) p[e] = fmaf(xv, gw[e * HD + h], p[e]);
    }
#pragma unroll
    for (int off = 32; off > 0; off >>= 1) {
#pragma unroll
        for (int e = 0; e < NE; e++) p[e] += __shfl_down(p[e], off, 64);
    }
    __shared__ float part[4][NE];
    int wave = tid >> 6, lane = tid & 63;
    if (lane == 0) {
#pragma unroll
        for (int e = 0; e < NE; e++) part[wave][e] = p[e];
    }
    __syncthreads();
    if (tid == 0) {
        float s[NE]; float sum = 0.f;
#pragma unroll
        for (int e = 0; e < NE; e++) {
            float l = part[0][e] + part[1][e] + part[2][e] + part[3][e];
            float sg = 1.f / (1.f + expf(-l));
            s[e] = sg; sum += sg;
        }
        int i1 = 0;
#pragma unroll
        for (int e = 1; e < NE; e++) if (s[e] > s[i1]) i1 = e;
        int i2 = (i1 == 0) ? 1 : 0;
#pragma unroll
        for (int e = 0; e < NE; e++) if (e != i1 && s[e] > s[i2]) i2 = e;
        float p1 = s[i1] / sum, p2 = s[i2] / sum;
        float inv = 1.f / (p1 + p2 + 1e-20f);
        topi[t * 2 + 0] = i1; topw[t * 2 + 0] = p1 * inv;
        topi[t * 2 + 1] = i2; topw[t * 2 + 1] = p2 * inv;
    }
}

// ---------------- compaction: one block per expert, deterministic ordered scan ----------------
__global__ __launch_bounds__(256) void compact_kernel(
    const int* __restrict__ topi, const float* __restrict__ topw,
    int* __restrict__ counts, int* __restrict__ pair_row, float* __restrict__ pair_w)
{
    const int e = blockIdx.x;
    const int tid = threadIdx.x;
    const int lane = tid & 63, wv = tid >> 6;
    __shared__ int wsum[4];
    int running = 0;
    for (int base = 0; base < 2 * TOK; base += 256) {
        const int idx = base + tid;
        const bool f = (topi[idx] == e);
        unsigned long long b = __ballot(f);
        int pre = __popcll(b & ((1ull << lane) - 1ull));
        if (lane == 0) wsum[wv] = __popcll(b);
        __syncthreads();
        int woff = 0;
#pragma unroll
        for (int w = 0; w < 4; w++) if (w < wv) woff += wsum[w];
        const int tot = wsum[0] + wsum[1] + wsum[2] + wsum[3];
        if (f) {
            const int pos = running + woff + pre;
            pair_row[e * CAP + pos] = idx;          // pair id = t*2+slot
            pair_w[e * CAP + pos] = topw[idx];
        }
        running += tot;
        __syncthreads();
    }
    if (tid == 0) counts[e] = running;
}

// ---------------- dequant + transpose: codes [E][K][N] int32 -> f16 [E][N][K] ----------------
template<int K, int N>
__global__ __launch_bounds__(256) void dequantT_kernel(
    const int* __restrict__ qw, const float* __restrict__ bsc, _Float16* __restrict__ wq)
{
    const int e = blockIdx.z, kt = blockIdx.y, nt = blockIdx.x;
    const int tid = threadIdx.x;
    __shared__ _Float16 T[64][68];   // [k][n]

    const int c4 = (tid & 15) * 4;
    const int r0 = tid >> 4;         // 0..15
#pragma unroll
    for (int p = 0; p < 4; p++) {
        const int r = p * 16 + r0;
        const int kabs = kt * 64 + r;
        const int4 c = *(const int4*)&qw[((size_t)e * K + kabs) * N + nt * 64 + c4];
        const float4 sc = *(const float4*)&bsc[((size_t)e * (K / QGROUP) + (kabs >> 4)) * N + nt * 64 + c4];
        half4v h;
        h[0] = (_Float16)((float)(c.x - 8) * sc.x);
        h[1] = (_Float16)((float)(c.y - 8) * sc.y);
        h[2] = (_Float16)((float)(c.z - 8) * sc.z);
        h[3] = (_Float16)((float)(c.w - 8) * sc.w);
        *(half4v*)&T[r][c4] = h;
    }
    __syncthreads();
    const int nrow = tid >> 2;
    const int kseg = (tid & 3) * 16;
    half8v o0, o1;
#pragma unroll
    for (int i = 0; i < 8; i++) o0[i] = T[kseg + i][nrow];
#pragma unroll
    for (int i = 0; i < 8; i++) o1[i] = T[kseg + 8 + i][nrow];
    _Float16* dst = wq + ((size_t)e * N + nt * 64 + nrow) * K + kt * 64 + kseg;
    *(half8v*)dst = o0;
    *(half8v*)(dst + 8) = o1;
}

// ---------------- gemm5: 64M x 128N x BK=64, XOR-swizzled conflict-free LDS, 5 blocks/CU ----------------
// LDS rows = 64 f16 = 128 B (full 32 banks). 16-B chunk c of row r stored at slot c^(r&7).
// 4 waves as 2x2: each wave 32M x 64N (2x4 frags), 16 MFMA per iter per wave.
template<int N, int K, bool UP>
__global__ __launch_bounds__(256, 5) void gemm5_kernel(
    const _Float16* __restrict__ A, const _Float16* __restrict__ BT,
    const float* __restrict__ gsc,
    const int* __restrict__ counts, const int* __restrict__ pair_row,
    const float* __restrict__ pair_w,
    _Float16* __restrict__ store16, float* __restrict__ store32)
{
    constexpr int NT = N / 128;
    constexpr int MT = CAP / 64;
    const int bx = blockIdx.x;
    const int g8 = bx & 7;                    // XCD hint
    const int rest = bx >> 3;
    const int m = rest % MT;
    const int g = (rest / MT) * 8 + g8;       // (NT*NE) multiple of 8
    const int e = g / NT, nt = g % NT;
    const int cnt = counts[e];
    const int mbase = m * 64;
    if (mbase >= cnt) return;
    const int nbase = nt * 128;
    const int tid = threadIdx.x;

    __shared__ _Float16 As[64 * 64];          // 8 KB
    __shared__ _Float16 Bs[128 * 64];         // 16 KB
    __shared__ int rows_s[64];
    __shared__ float pw_s[64];

    if (tid < 64) {
        int idx = mbase + tid; if (idx >= cnt) idx = cnt - 1;
        rows_s[tid] = pair_row[e * CAP + idx];
        pw_s[tid] = UP ? pair_w[e * CAP + idx] : 0.f;
    }
    __syncthreads();

    // staging maps (granule = 16 B = 8 f16). A: 512 granules (2/thread), B: 1024 (4/thread).
    const _Float16* asrc[2]; _Float16* adst[2];
#pragma unroll
    for (int j = 0; j < 2; j++) {
        const int gidx = j * 256 + tid;
        const int r = gidx >> 3, s = gidx & 7, c = s ^ (r & 7);
        const int pr = rows_s[r];
        asrc[j] = A + (size_t)(UP ? (pr >> 1) : pr) * K + c * 8;
        adst[j] = &As[r * 64 + s * 8];
    }
    const _Float16* bsrc[4]; _Float16* bdst[4];
#pragma unroll
    for (int j = 0; j < 4; j++) {
        const int gidx = j * 256 + tid;
        const int r = gidx >> 3, s = gidx & 7, c = s ^ (r & 7);
        bsrc[j] = BT + ((size_t)e * N + nbase + r) * K + c * 8;
        bdst[j] = &Bs[r * 64 + s * 8];
    }

    const int lane = tid & 63, wv = tid >> 6;
    const int quad = lane >> 4, lm = lane & 15;
    const int wm = (wv & 1) * 32, wn = (wv >> 1) * 64;

    float4v acc[2][4];
#pragma unroll
    for (int mi = 0; mi < 2; mi++)
#pragma unroll
        for (int ni = 0; ni < 4; ni++) acc[mi][ni] = (float4v){0.f, 0.f, 0.f, 0.f};

    for (int k0 = 0; k0 < K; k0 += 64) {
#pragma unroll
        for (int j = 0; j < 2; j++) g2l16(asrc[j] + k0, adst[j]);
#pragma unroll
        for (int j = 0; j < 4; j++) g2l16(bsrc[j] + k0, bdst[j]);
        __syncthreads();
#pragma unroll
        for (int ks = 0; ks < 2; ks++) {
            half8v af[2], bf[4];
#pragma unroll
            for (int mi = 0; mi < 2; mi++) {
                const int r = wm + mi * 16 + lm;
                const int s = (ks * 4 + quad) ^ (r & 7);
                af[mi] = *(const half8v*)&As[r * 64 + s * 8];
            }
#pragma unroll
            for (int ni = 0; ni < 4; ni++) {
                const int r = wn + ni * 16 + lm;
                const int s = (ks * 4 + quad) ^ (r & 7);
                bf[ni] = *(const half8v*)&Bs[r * 64 + s * 8];
            }
#pragma unroll
            for (int mi = 0; mi < 2; mi++)
#pragma unroll
                for (int ni = 0; ni < 4; ni++)
                    acc[mi][ni] = __builtin_amdgcn_mfma_f32_16x16x32_f16(af[mi], bf[ni], acc[mi][ni], 0, 0, 0);
        }
        __syncthreads();
    }

    const float gs = gsc[0];
#pragma unroll
    for (int mi = 0; mi < 2; mi++) {
#pragma unroll
        for (int r = 0; r < 4; r++) {
            const int rl = wm + mi * 16 + quad * 4 + r;
            if (mbase + rl < cnt) {
                const int pr = rows_s[rl];
#pragma unroll
                for (int ni = 0; ni < 4; ni++) {
                    const int col = nbase + wn + ni * 16 + lm;
                    float v = acc[mi][ni][r] * gs;
                    if (UP) {
                        v = fmaxf(v, 0.f);
                        v = v * v * pw_s[rl];
                        store16[(size_t)pr * N + col] = (_Float16)v;
                    } else {
                        atomicAdd(&store32[(size_t)(pr >> 1) * N + col], v);
                    }
                }
            }
        }
    }
}

// ---------------- fallback fused-dequant GEMM (round-4 structure) ----------------
template<int N, int K, bool UP>
__global__ __launch_bounds__(256) void gemm_fused_kernel(
    const _Float16* __restrict__ A, const int* __restrict__ qw,
    const float* __restrict__ bsc, const float* __restrict__ gsc,
    const int* __restrict__ counts, const int* __restrict__ pair_row,
    const float* __restrict__ pair_w,
    _Float16* __restrict__ store16, float* __restrict__ store32)
{
    constexpr int NT = N / 128;
    const int e = blockIdx.y;
    const int cnt = counts[e];
    const int mt = blockIdx.x / NT, nt = blockIdx.x % NT;
    const int mbase = mt * 128;
    if (mbase >= cnt) return;
    const int nbase = nt * 128;
    const int tid = threadIdx.x;

    __shared__ _Float16 As[128][40];
    __shared__ _Float16 Bs[128][40];
    __shared__ int rows_s[128];
    __shared__ float pw_s[128];

    if (tid < 128) {
        int idx = mbase + tid; if (idx >= cnt) idx = cnt - 1;
        rows_s[tid] = pair_row[e * CAP + idx];
        pw_s[tid] = UP ? pair_w[e * CAP + idx] : 0.f;
    }

    const int lane = tid & 63, wv = tid >> 6;
    const int quad = lane >> 4, lm = lane & 15;
    const int wr = (wv >> 1) * 64, wc = (wv & 1) * 64;

    float4v acc[4][4];
#pragma unroll
    for (int mi = 0; mi < 4; mi++)
#pragma unroll
        for (int ni = 0; ni < 4; ni++) acc[mi][ni] = (float4v){0.f, 0.f, 0.f, 0.f};

    const int am = tid & 127, akk = (tid >> 7) * 16;
    const int bn4 = (tid & 31) * 4, bkb = (tid >> 5) * 4;

    for (int k0 = 0; k0 < K; k0 += 32) {
        __syncthreads();
        {
            int pr = rows_s[am];
            const _Float16* src = A + (size_t)(UP ? (pr >> 1) : pr) * K + k0 + akk;
            *(uint4*)&As[am][akk] = *(const uint4*)src;
            *(uint4*)&As[am][akk + 8] = *(const uint4*)(src + 8);
        }
        {
            const int kabs = k0 + bkb;
            const float4 sc = *(const float4*)&bsc[((size_t)e * (K / QGROUP) + (kabs >> 4)) * N + nbase + bn4];
            const int4 c0 = *(const int4*)&qw[((size_t)e * K + kabs + 0) * N + nbase + bn4];
            const int4 c1 = *(const int4*)&qw[((size_t)e * K + kabs + 1) * N + nbase + bn4];
            const int4 c2 = *(const int4*)&qw[((size_t)e * K + kabs + 2) * N + nbase + bn4];
            const int4 c3 = *(const int4*)&qw[((size_t)e * K + kabs + 3) * N + nbase + bn4];
            half4v q;
            q[0] = (_Float16)((c0.x - 8) * sc.x); q[1] = (_Float16)((c1.x - 8) * sc.x);
            q[2] = (_Float16)((c2.x - 8) * sc.x); q[3] = (_Float16)((c3.x - 8) * sc.x);
            *(half4v*)&Bs[bn4 + 0][bkb] = q;
            q[0] = (_Float16)((c0.y - 8) * sc.y); q[1] = (_Float16)((c1.y - 8) * sc.y);
            q[2] = (_Float16)((c2.y - 8) * sc.y); q[3] = (_Float16)((c3.y - 8) * sc.y);
            *(half4v*)&Bs[bn4 + 1][bkb] = q;
            q[0] = (_Float16)((c0.z - 8) * sc.z); q[1] = (_Float16)((c1.z - 8) * sc.z);
            q[2] = (_Float16)((c2.z - 8) * sc.z); q[3] = (_Float16)((c3.z - 8) * sc.z);
            *(half4v*)&Bs[bn4 + 2][bkb] = q;
            q[0] = (_Float16)((c0.w - 8) * sc.w); q[1] = (_Float16)((c1.w - 8) * sc.w);
            q[2] = (_Float16)((c2.w - 8) * sc.w); q[3] = (_Float16)((c3.w - 8) * sc.w);
            *(half4v*)&Bs[bn4 + 3][bkb] = q;
        }
        __syncthreads();
        half8v af[4], bf[4];
#pragma unroll
        for (int mi = 0; mi < 4; mi++)
            af[mi] = *(const half8v*)&As[wr + mi * 16 + lm][quad * 8];
#pragma unroll
        for (int ni = 0; ni < 4; ni++)
            bf[ni] = *(const half8v*)&Bs[wc + ni * 16 + lm][quad * 8];
#pragma unroll
        for (int mi = 0; mi < 4; mi++)
#pragma unroll
            for (int ni = 0; ni < 4; ni++)
                acc[mi][ni] = __builtin_amdgcn_mfma_f32_16x16x32_f16(af[mi], bf[ni], acc[mi][ni], 0, 0, 0);
    }

    const float gs = gsc[0];
#pragma unroll
    for (int mi = 0; mi < 4; mi++) {
#pragma unroll
        for (int r = 0; r < 4; r++) {
            const int rl = wr + mi * 16 + quad * 4 + r;
            if (mbase + rl < cnt) {
                const int pr = rows_s[rl];
#pragma unroll
                for (int ni = 0; ni < 4; ni++) {
                    const int col = nbase + wc + ni * 16 + lm;
                    float v = acc[mi][ni][r] * gs;
                    if (UP) {
                        v = fmaxf(v, 0.f);
                        v = v * v * pw_s[rl];
                        store16[(size_t)pr * N + col] = (_Float16)v;
                    } else {
                        atomicAdd(&store32[(size_t)(pr >> 1) * N + col], v);
                    }
                }
            }
        }
    }
}

extern "C" void kernel_launch(void* const* d_in, const int* in_sizes, int n_in,
                              void* d_out, int out_size, void* d_ws, size_t ws_size,
                              hipStream_t stream) {
    const float* x   = (const float*)d_in[0];
    const float* gw  = (const float*)d_in[1];
    const float* usc = (const float*)d_in[2];
    const float* ugs = (const float*)d_in[3];
    const float* dsc = (const float*)d_in[4];
    const float* dgs = (const float*)d_in[5];
    const int*   uq  = (const int*)d_in[6];
    const int*   dq  = (const int*)d_in[7];
    float* out = (float*)d_out;

    char* ws = (char*)d_ws;
    int*   counts   = (int*)(ws + 0);
    int*   pair_row = (int*)(ws + 4096);
    float* pair_w   = (float*)(ws + 4096 + (size_t)NE * CAP * 4);        // @266240
    _Float16* xh    = (_Float16*)(ws + 528384);                          // TOK*HD f16 (16.78 MB)
    _Float16* act   = (_Float16*)(ws + 528384 + (size_t)TOK * HD * 2);   // 2*TOK*ID f16 @17.3 MB
    _Float16* wq    = (_Float16*)(ws + 528384 + (size_t)TOK * HD * 2
                                  + (size_t)2 * TOK * ID * 2);           // @34.1 MB, 67.1 MB (reused)
    // topi/topw alias the wq region (lifetime: router -> compact, before dequant writes wq)
    int*   topi = (int*)wq;
    float* topw = (float*)((char*)wq + (size_t)2 * TOK * 4);
    const size_t need_deq = 34082816ull + (size_t)NE * HD * ID * 2;      // ~101.2 MB (confirmed fits)
    const bool use_deq = ws_size >= need_deq;

    hipMemsetAsync(out, 0, (size_t)TOK * HD * 4, stream);   // down-proj accumulates atomically

    prep_kernel<<<(TOK * HD) / (256 * 8), 256, 0, stream>>>(x, xh);
    router_kernel<<<TOK, 256, 0, stream>>>(x, gw, topi, topw);
    compact_kernel<<<NE, 256, 0, stream>>>(topi, topw, counts, pair_row, pair_w);

    if (use_deq) {
        // up: K=HD=2048, N=ID=1024
        dequantT_kernel<HD, ID><<<dim3(ID / 64, HD / 64, NE), 256, 0, stream>>>(uq, usc, wq);
        gemm5_kernel<ID, HD, true><<<(CAP / 64) * (ID / 128) * NE, 256, 0, stream>>>(
            xh, wq, ugs, counts, pair_row, pair_w, act, nullptr);
        // down: K=ID=1024, N=HD=2048 (reuse wq)
        dequantT_kernel<ID, HD><<<dim3(HD / 64, ID / 64, NE), 256, 0, stream>>>(dq, dsc, wq);
        gemm5_kernel<HD, ID, false><<<(CAP / 64) * (HD / 128) * NE, 256, 0, stream>>>(
            act, wq, dgs, counts, pair_row, pair_w, nullptr, out);
    } else {
        gemm_fused_kernel<ID, HD, true><<<dim3((CAP / 128) * (ID / 128), NE), 256, 0, stream>>>(
            xh, uq, usc, ugs, counts, pair_row, pair_w, act, nullptr);
        gemm_fused_kernel<HD, ID, false><<<dim3((CAP / 128) * (HD / 128), NE), 256, 0, stream>>>(
            act, dq, dsc, dgs, counts, pair_row, pair_w, nullptr, out);
    }
}